// Round 1
// baseline (856.230 us; speedup 1.0000x reference)
//
#include <hip/hip_runtime.h>
#include <math.h>

// ---------------------------------------------------------------------------
// TransformerEncoder on MI355X (gfx950).
// Numerical strategy: bf16 MFMA everywhere, but the path feeding softmax
// (h -> q,k -> scores) uses hi/lo bf16-split GEMMs (3 MFMA products) for
// ~fp32 accuracy, because SCALE=sqrt(197) makes softmax near-argmax.
// ---------------------------------------------------------------------------

#define S_LEN 197
#define DIM   768
#define HDIM  3072
#define BATCH 64
#define NT    (BATCH * S_LEN)   // 12608 tokens
#define NTP   12672             // NT padded to multiple of 128
#define SD    (S_LEN * DIM)     // 151296 elements per batch sample
#define SROWS 208               // scores ws rows per batch (alloc)
#define SCOLS 224               // scores/P cols per batch (K-pad for PV, mult of 32)
#define PROWS 256               // P ws rows per batch (alloc, covers 2x128 tiles)

typedef __attribute__((ext_vector_type(4))) float  f32x4;
typedef __attribute__((ext_vector_type(8))) short  short8v;
typedef __attribute__((ext_vector_type(4))) short  short4v;
typedef __attribute__((ext_vector_type(4))) unsigned short ushort4v;

__device__ __forceinline__ ushort f2bf(float f) {   // RNE float->bf16 bits
  union { float f; unsigned u; } a; a.f = f;
  unsigned u = a.u;
  u += 0x7FFFu + ((u >> 16) & 1u);
  return (ushort)(u >> 16);
}
__device__ __forceinline__ float b2f(ushort h) {
  union { unsigned u; float f; } a; a.u = ((unsigned)h) << 16;
  return a.f;
}
__device__ __forceinline__ float gelu_f(float x) {  // exact gelu
  return 0.5f * x * (1.0f + erff(x * 0.7071067811865476f));
}

// ---------------------------------------------------------------------------
// Weight transpose + bf16 (hi[/lo]) split:  W[K][N] -> T[N][K]
// ---------------------------------------------------------------------------
template<bool SPLIT>
__global__ __launch_bounds__(256) void transp_k(const float* __restrict__ W,
                                                int K, int N,
                                                ushort* __restrict__ Thi,
                                                ushort* __restrict__ Tlo) {
  __shared__ float tile[32][33];
  const int nb = blockIdx.x * 32, kb = blockIdx.y * 32;
  const int tx = threadIdx.x, ty = threadIdx.y;   // (32, 8)
#pragma unroll
  for (int i = 0; i < 4; ++i)
    tile[ty + i * 8][tx] = W[(size_t)(kb + ty + i * 8) * N + nb + tx];
  __syncthreads();
#pragma unroll
  for (int i = 0; i < 4; ++i) {
    float v = tile[tx][ty + i * 8];             // = W[kb+tx][nb+ty+i*8]
    size_t o = (size_t)(nb + ty + i * 8) * K + kb + tx;
    ushort h = f2bf(v);
    Thi[o] = h;
    if (SPLIT) Tlo[o] = f2bf(v - b2f(h));
  }
}

// ---------------------------------------------------------------------------
// LayerNorm over (S,D) per batch sample, elementwise affine, bf16 out (hi[/lo])
// ---------------------------------------------------------------------------
template<bool SPLIT>
__global__ __launch_bounds__(1024) void ln_k(const float* __restrict__ x,
                                             const float* __restrict__ w,
                                             const float* __restrict__ bb,
                                             ushort* __restrict__ oHi,
                                             ushort* __restrict__ oLo) {
  const int b = blockIdx.x;
  const float4* xv = (const float4*)(x + (size_t)b * SD);
  const int N4 = SD / 4;
  float sum = 0.f, sq = 0.f;
  for (int i = threadIdx.x; i < N4; i += 1024) {
    float4 v = xv[i];
    sum += (v.x + v.y) + (v.z + v.w);
    sq  += (v.x * v.x + v.y * v.y) + (v.z * v.z + v.w * v.w);
  }
#pragma unroll
  for (int off = 32; off > 0; off >>= 1) {
    sum += __shfl_xor(sum, off);
    sq  += __shfl_xor(sq, off);
  }
  __shared__ float s1[16], s2[16];
  __shared__ float sMu, sRs;
  const int wv = threadIdx.x >> 6;
  if ((threadIdx.x & 63) == 0) { s1[wv] = sum; s2[wv] = sq; }
  __syncthreads();
  if (threadIdx.x == 0) {
    float Sm = 0.f, Q = 0.f;
#pragma unroll
    for (int i = 0; i < 16; ++i) { Sm += s1[i]; Q += s2[i]; }
    float mu = Sm / (float)SD;
    float var = Q / (float)SD - mu * mu;
    sMu = mu;
    sRs = 1.0f / sqrtf(var + 1e-5f);
  }
  __syncthreads();
  const float mu = sMu, rs = sRs;
  const float4* wv4 = (const float4*)w;
  const float4* bv4 = (const float4*)bb;
  ushort4v* oH = (ushort4v*)(oHi + (size_t)b * SD);
  ushort4v* oL = SPLIT ? (ushort4v*)(oLo + (size_t)b * SD) : nullptr;
  for (int i = threadIdx.x; i < N4; i += 1024) {
    float4 v = xv[i], W4 = wv4[i], B4 = bv4[i];
    float h0 = (v.x - mu) * rs * W4.x + B4.x;
    float h1 = (v.y - mu) * rs * W4.y + B4.y;
    float h2 = (v.z - mu) * rs * W4.z + B4.z;
    float h3 = (v.w - mu) * rs * W4.w + B4.w;
    ushort4v hh;
    hh[0] = f2bf(h0); hh[1] = f2bf(h1); hh[2] = f2bf(h2); hh[3] = f2bf(h3);
    oH[i] = hh;
    if (SPLIT) {
      ushort4v ll;
      ll[0] = f2bf(h0 - b2f(hh[0]));
      ll[1] = f2bf(h1 - b2f(hh[1]));
      ll[2] = f2bf(h2 - b2f(hh[2]));
      ll[3] = f2bf(h3 - b2f(hh[3]));
      oL[i] = ll;
    }
  }
}

// ---------------------------------------------------------------------------
// Row softmax over 197 valid cols; writes P (bf16) with cols [197,224) zeroed
// ---------------------------------------------------------------------------
__global__ __launch_bounds__(64) void softmax_k(const float* __restrict__ scores,
                                                ushort* __restrict__ P) {
  const int s = blockIdx.x, b = blockIdx.y;
  const int lane = threadIdx.x;
  const float* row = scores + ((size_t)b * SROWS + s) * SCOLS;
  float v[4];
  float m = -1e30f;
#pragma unroll
  for (int t = 0; t < 4; ++t) {
    int c = lane + t * 64;
    v[t] = (c < S_LEN) ? row[c] : -1e30f;
    m = fmaxf(m, v[t]);
  }
#pragma unroll
  for (int off = 32; off > 0; off >>= 1) m = fmaxf(m, __shfl_xor(m, off));
  float sum = 0.f;
#pragma unroll
  for (int t = 0; t < 4; ++t) {
    int c = lane + t * 64;
    v[t] = (c < S_LEN) ? expf(v[t] - m) : 0.f;
    sum += v[t];
  }
#pragma unroll
  for (int off = 32; off > 0; off >>= 1) sum += __shfl_xor(sum, off);
  const float inv = 1.0f / sum;
  ushort* prow = P + ((size_t)b * PROWS + s) * SCOLS;
#pragma unroll
  for (int t = 0; t < 4; ++t) {
    int c = lane + t * 64;
    if (c < SCOLS) prow[c] = f2bf(v[t] * inv);
  }
}

// ---------------------------------------------------------------------------
// Generic MFMA GEMM: C[M][N] = A[M][K] * B^T (B stored [N][K] unless TRANSB,
// then B stored [K][N] and transposed during LDS staging).
// NPROD==3: hi/lo split products (Ahi*Bhi + Ahi*Blo + Alo*Bhi).
// Tile 128x128x32, 256 threads (4 waves, 2x2), mfma_f32_16x16x32_bf16.
// ---------------------------------------------------------------------------
#define GBM 128
#define GBN 128
#define GBK 32
#define LSTR 56   // 32 + 24 pad: 112B row stride (16B aligned, ~2-way banks)

enum { EPI_QK = 0, EPI_V, EPI_SCORE, EPI_PV, EPI_GELU, EPI_OUT };

struct GemmArgs {
  const ushort* Ahi; const ushort* Alo; size_t sAb; int lda;
  const ushort* Bhi; const ushort* Blo; size_t sBb; int ldb;
  int K; int Mv; int Nv;
  const float* bias;
  const float* resid; size_t sRb; int ldr;
  float scale;
  float* outF; size_t sOb; int ldo;
  ushort* outHi; ushort* outLo;
};

__device__ __forceinline__ short8v load_frag(const ushort* p) {
  union U { short8v v8; struct P4 { short4v a, b; } p4; } f;
  f.p4.a = *(const short4v*)(p);        // k-block 0: k = 4*g + [0..3]
  f.p4.b = *(const short4v*)(p + 16);   // k-block 1: k = 16 + 4*g + [0..3]
  return f.v8;
}

template<int NPROD, bool TRANSB, int EPI>
__global__ __launch_bounds__(256) void gemm_k(GemmArgs g) {
  const int tid  = threadIdx.x;
  const int lane = tid & 63;
  const int wid  = tid >> 6;
  const int r    = lane & 15;     // A row / B col / C col
  const int gg   = lane >> 4;     // k-group; C row group
  const int wrow = wid >> 1;
  const int wcol = wid & 1;
  const int nbase = blockIdx.x * GBN;
  const int mbase = blockIdx.y * GBM;
  const int b     = blockIdx.z;

  const ushort* Ahi = g.Ahi + (size_t)b * g.sAb;
  const ushort* Bhi = g.Bhi + (size_t)b * g.sBb;
  const ushort* Alo = (NPROD == 3) ? (g.Alo + (size_t)b * g.sAb) : (const ushort*)nullptr;
  const ushort* Blo = (NPROD == 3) ? (g.Blo + (size_t)b * g.sBb) : (const ushort*)nullptr;

  __shared__ ushort sm[(NPROD == 3 ? 4 : 2) * GBM * LSTR];
  ushort* sAhi = sm;
  ushort* sBhi = sm + GBM * LSTR;
  ushort* sAlo = (NPROD == 3) ? (sm + 2 * GBM * LSTR) : (ushort*)nullptr;
  ushort* sBlo = (NPROD == 3) ? (sm + 3 * GBM * LSTR) : (ushort*)nullptr;

  f32x4 acc[4][4];
#pragma unroll
  for (int i = 0; i < 4; ++i)
#pragma unroll
    for (int j = 0; j < 4; ++j) {
      acc[i][j][0] = 0.f; acc[i][j][1] = 0.f; acc[i][j][2] = 0.f; acc[i][j][3] = 0.f;
    }

  for (int kk = 0; kk < g.K; kk += GBK) {
    __syncthreads();
    // ---- stage A (and B) tiles into LDS, 8 bf16 (16B) per thread per round
#pragma unroll
    for (int rd = 0; rd < 2; ++rd) {
      const int lin = tid * 8 + rd * 2048;
      {
        const int row = lin >> 5, col = lin & 31;
        const size_t go = (size_t)(mbase + row) * g.lda + (kk + col);
        *(short8v*)(sAhi + row * LSTR + col) = *(const short8v*)(Ahi + go);
        if (NPROD == 3)
          *(short8v*)(sAlo + row * LSTR + col) = *(const short8v*)(Alo + go);
      }
      if (!TRANSB) {
        const int row = lin >> 5, col = lin & 31;
        const size_t go = (size_t)(nbase + row) * g.ldb + (kk + col);
        *(short8v*)(sBhi + row * LSTR + col) = *(const short8v*)(Bhi + go);
        if (NPROD == 3)
          *(short8v*)(sBlo + row * LSTR + col) = *(const short8v*)(Blo + go);
      } else {
        // B stored [K][N]: read coalesced along N, transpose into LDS [n][k]
        const int kr = lin >> 7, nc = lin & 127;
        union { short8v v; ushort u[8]; } t;
        t.v = *(const short8v*)(Bhi + (size_t)(kk + kr) * g.ldb + (nbase + nc));
#pragma unroll
        for (int e = 0; e < 8; ++e)
          sBhi[(nc + e) * LSTR + kr] = t.u[e];
      }
    }
    __syncthreads();

    // ---- fragments + MFMA
    short8v aH[4], bH[4], aL[4], bL[4];
#pragma unroll
    for (int i = 0; i < 4; ++i) {
      const int off = (wrow * 64 + i * 16 + r) * LSTR + gg * 4;
      aH[i] = load_frag(sAhi + off);
      if (NPROD == 3) aL[i] = load_frag(sAlo + off);
    }
#pragma unroll
    for (int j = 0; j < 4; ++j) {
      const int off = (wcol * 64 + j * 16 + r) * LSTR + gg * 4;
      bH[j] = load_frag(sBhi + off);
      if (NPROD == 3) bL[j] = load_frag(sBlo + off);
    }
#pragma unroll
    for (int i = 0; i < 4; ++i)
#pragma unroll
      for (int j = 0; j < 4; ++j) {
        acc[i][j] = __builtin_amdgcn_mfma_f32_16x16x32_bf16(aH[i], bH[j], acc[i][j], 0, 0, 0);
        if (NPROD == 3) {
          acc[i][j] = __builtin_amdgcn_mfma_f32_16x16x32_bf16(aH[i], bL[j], acc[i][j], 0, 0, 0);
          acc[i][j] = __builtin_amdgcn_mfma_f32_16x16x32_bf16(aL[i], bH[j], acc[i][j], 0, 0, 0);
        }
      }
  }

  // ---- epilogue.  C/D layout: col = lane&15, row = (lane>>4)*4 + reg
#pragma unroll
  for (int i = 0; i < 4; ++i)
#pragma unroll
    for (int j = 0; j < 4; ++j)
#pragma unroll
      for (int e = 0; e < 4; ++e) {
        const int row = mbase + wrow * 64 + i * 16 + gg * 4 + e;
        const int col = nbase + wcol * 64 + j * 16 + r;
        float val = acc[i][j][e];
        if (EPI == EPI_QK) {
          val += g.bias[col];
          ushort hi = f2bf(val);
          ushort lo = f2bf(val - b2f(hi));
          size_t o = (size_t)row * g.ldo + col;
          g.outHi[o] = hi; g.outLo[o] = lo;
        } else if (EPI == EPI_V) {
          val += g.bias[col];
          g.outHi[(size_t)row * g.ldo + col] = f2bf(val);
        } else if (EPI == EPI_SCORE) {
          if (row < g.Mv && col < g.Nv)
            (g.outF + (size_t)b * g.sOb)[(size_t)row * g.ldo + col] = val * g.scale;
        } else if (EPI == EPI_PV) {
          if (row < g.Mv) {
            val += (g.resid + (size_t)b * g.sRb)[(size_t)row * g.ldr + col];
            (g.outF + (size_t)b * g.sOb)[(size_t)row * g.ldo + col] = val;
          }
        } else if (EPI == EPI_GELU) {
          val = gelu_f(val + g.bias[col]);
          g.outHi[(size_t)row * g.ldo + col] = f2bf(val);
        } else { // EPI_OUT
          if (row < g.Mv) {
            val = gelu_f(val + g.bias[col]);
            val += g.resid[(size_t)row * g.ldr + col];
            g.outF[(size_t)row * g.ldo + col] = val;
          }
        }
      }
}

// ---------------------------------------------------------------------------
// Host side
// ---------------------------------------------------------------------------
extern "C" void kernel_launch(void* const* d_in, const int* in_sizes, int n_in,
                              void* d_out, int out_size, void* d_ws, size_t ws_size,
                              hipStream_t stream) {
  const float* x   = (const float*)d_in[0];
  const float* n1w = (const float*)d_in[1];
  const float* n1b = (const float*)d_in[2];
  const float* Wq  = (const float*)d_in[3];
  const float* bq  = (const float*)d_in[4];
  const float* Wk  = (const float*)d_in[5];
  const float* bk  = (const float*)d_in[6];
  const float* Wv  = (const float*)d_in[7];
  const float* bv  = (const float*)d_in[8];
  const float* n2w = (const float*)d_in[9];
  const float* n2b = (const float*)d_in[10];
  const float* W1  = (const float*)d_in[11];
  const float* b1  = (const float*)d_in[12];
  const float* W2  = (const float*)d_in[13];
  const float* b2  = (const float*)d_in[14];
  float* out = (float*)d_out;

  char* ws = (char*)d_ws;
  size_t off = 0;
  auto alloc = [&](size_t bytes) -> char* {
    char* p = ws + off;
    off += (bytes + 255) & ~(size_t)255;
    return p;
  };
  const size_t szDD  = (size_t)DIM * DIM * 2;      // 768x768 bf16
  const size_t szDH  = (size_t)DIM * HDIM * 2;     // 768x3072 bf16
  const size_t szAct = (size_t)NTP * DIM * 2;      // padded activation bf16

  ushort* wqtH = (ushort*)alloc(szDD);
  ushort* wqtL = (ushort*)alloc(szDD);
  ushort* wktH = (ushort*)alloc(szDD);
  ushort* wktL = (ushort*)alloc(szDD);
  ushort* wvtH = (ushort*)alloc(szDD);
  ushort* w1tH = (ushort*)alloc(szDH);
  ushort* w2tH = (ushort*)alloc(szDH);
  ushort* hHi  = (ushort*)alloc(szAct);
  ushort* hLo  = (ushort*)alloc(szAct);
  ushort* qHi  = (ushort*)alloc(szAct);
  ushort* qLo  = (ushort*)alloc(szAct);
  ushort* kHi  = (ushort*)alloc(szAct);
  ushort* kLo  = (ushort*)alloc(szAct);
  ushort* vB   = (ushort*)alloc(szAct);
  float*  scoresWs = (float*)alloc((size_t)BATCH * SROWS * SCOLS * 4);
  ushort* pWs      = (ushort*)alloc((size_t)BATCH * PROWS * SCOLS * 2);
  if (off > ws_size) return;  // workspace too small -> fail loudly in validation

  // Aliases (lifetimes disjoint):
  float*  x2  = (float*)hHi;   // 12672*768*4 == 2 * szAct
  ushort* h2  = vB;            // after PV, v no longer needed
  ushort* hid = qHi;           // 12672*3072*2 == 4 * szAct (q/k hi/lo block)

  const float SCALE_F = 14.035668847618199f;  // sqrt(197) == 1/S**(-0.5)

  dim3 tb(32, 8);
  hipLaunchKernelGGL((transp_k<true >), dim3(DIM / 32, DIM / 32), tb, 0, stream, Wq, DIM, DIM, wqtH, wqtL);
  hipLaunchKernelGGL((transp_k<true >), dim3(DIM / 32, DIM / 32), tb, 0, stream, Wk, DIM, DIM, wktH, wktL);
  hipLaunchKernelGGL((transp_k<false>), dim3(DIM / 32, DIM / 32), tb, 0, stream, Wv, DIM, DIM, wvtH, (ushort*)nullptr);
  hipLaunchKernelGGL((transp_k<false>), dim3(HDIM / 32, DIM / 32), tb, 0, stream, W1, DIM, HDIM, w1tH, (ushort*)nullptr);
  hipLaunchKernelGGL((transp_k<false>), dim3(DIM / 32, HDIM / 32), tb, 0, stream, W2, HDIM, DIM, w2tH, (ushort*)nullptr);

  hipLaunchKernelGGL((ln_k<true>), dim3(BATCH), dim3(1024), 0, stream, x, n1w, n1b, hHi, hLo);

  GemmArgs a;
  const int BIG = 0x40000000;

  // Q projection (split)
  a = GemmArgs{};
  a.Ahi = hHi; a.Alo = hLo; a.sAb = 0; a.lda = DIM;
  a.Bhi = wqtH; a.Blo = wqtL; a.sBb = 0; a.ldb = DIM;
  a.K = DIM; a.Mv = BIG; a.Nv = BIG; a.bias = bq; a.scale = 1.f;
  a.outHi = qHi; a.outLo = qLo; a.ldo = DIM;
  hipLaunchKernelGGL((gemm_k<3, false, EPI_QK>), dim3(DIM / GBN, NTP / GBM, 1), dim3(256), 0, stream, a);
  // K projection (split)
  a.Bhi = wktH; a.Blo = wktL; a.bias = bk; a.outHi = kHi; a.outLo = kLo;
  hipLaunchKernelGGL((gemm_k<3, false, EPI_QK>), dim3(DIM / GBN, NTP / GBM, 1), dim3(256), 0, stream, a);
  // V projection (single)
  a = GemmArgs{};
  a.Ahi = hHi; a.sAb = 0; a.lda = DIM;
  a.Bhi = wvtH; a.sBb = 0; a.ldb = DIM;
  a.K = DIM; a.Mv = BIG; a.Nv = BIG; a.bias = bv;
  a.outHi = vB; a.ldo = DIM;
  hipLaunchKernelGGL((gemm_k<1, false, EPI_V>), dim3(DIM / GBN, NTP / GBM, 1), dim3(256), 0, stream, a);

  // scores = SCALE * q k^T  (batched, split)
  a = GemmArgs{};
  a.Ahi = qHi; a.Alo = qLo; a.sAb = (size_t)SD; a.lda = DIM;
  a.Bhi = kHi; a.Blo = kLo; a.sBb = (size_t)SD; a.ldb = DIM;
  a.K = DIM; a.Mv = S_LEN; a.Nv = S_LEN; a.scale = SCALE_F;
  a.outF = scoresWs; a.sOb = (size_t)SROWS * SCOLS; a.ldo = SCOLS;
  hipLaunchKernelGGL((gemm_k<3, false, EPI_SCORE>), dim3(2, 2, BATCH), dim3(256), 0, stream, a);

  hipLaunchKernelGGL(softmax_k, dim3(S_LEN, BATCH), dim3(64), 0, stream, scoresWs, pWs);

  // x2 = P v + x  (batched; B = v stored [K][N] -> TRANSB staging)
  a = GemmArgs{};
  a.Ahi = pWs; a.sAb = (size_t)PROWS * SCOLS; a.lda = SCOLS;
  a.Bhi = vB; a.sBb = (size_t)SD; a.ldb = DIM;
  a.K = SCOLS; a.Mv = S_LEN; a.Nv = BIG;
  a.resid = x; a.sRb = (size_t)SD; a.ldr = DIM;
  a.outF = x2; a.sOb = (size_t)SD; a.ldo = DIM;
  hipLaunchKernelGGL((gemm_k<1, true, EPI_PV>), dim3(DIM / GBN, 2, BATCH), dim3(256), 0, stream, a);

  hipLaunchKernelGGL((ln_k<false>), dim3(BATCH), dim3(1024), 0, stream, x2, n2w, n2b, h2, (ushort*)nullptr);

  // hid = gelu(h2 W1 + b1)
  a = GemmArgs{};
  a.Ahi = h2; a.sAb = 0; a.lda = DIM;
  a.Bhi = w1tH; a.sBb = 0; a.ldb = DIM;
  a.K = DIM; a.Mv = BIG; a.Nv = BIG; a.bias = b1;
  a.outHi = hid; a.ldo = HDIM;
  hipLaunchKernelGGL((gemm_k<1, false, EPI_GELU>), dim3(HDIM / GBN, NTP / GBM, 1), dim3(256), 0, stream, a);

  // out = gelu(hid W2 + b2) + x2
  a = GemmArgs{};
  a.Ahi = hid; a.sAb = 0; a.lda = HDIM;
  a.Bhi = w2tH; a.sBb = 0; a.ldb = HDIM;
  a.K = HDIM; a.Mv = NT; a.Nv = BIG; a.bias = b2;
  a.resid = x2; a.sRb = 0; a.ldr = DIM;
  a.outF = out; a.sOb = 0; a.ldo = DIM;
  hipLaunchKernelGGL((gemm_k<1, false, EPI_OUT>), dim3(DIM / GBN, NTP / GBM, 1), dim3(256), 0, stream, a);
}